// Round 4
// baseline (247.341 us; speedup 1.0000x reference)
//
#include <hip/hip_runtime.h>
#include <cstdint>
#include <cstddef>

#define RHO 1e-8f
#define EPSV 1e-8f
#define THRESH 0.9f

typedef float v2f __attribute__((ext_vector_type(2)));

__device__ __forceinline__ float wave_max(float v) {
#pragma unroll
  for (int off = 1; off < 64; off <<= 1) v = fmaxf(v, __shfl_xor(v, off, 64));
  return v;
}

// Raw workgroup barrier WITHOUT the compiler's vmcnt(0) drain: only LDS ops
// must be visible across it (lgkmcnt(0)); outstanding global prefetches stay
// in flight (T3/T4 counted-wait pattern). sched_barrier(0) fences the machine
// scheduler (rule #18); the "memory" clobber fences IR-level motion.
__device__ __forceinline__ void lds_barrier() {
  asm volatile("s_waitcnt lgkmcnt(0)" ::: "memory");
  __builtin_amdgcn_sched_barrier(0);
  __builtin_amdgcn_s_barrier();
  __builtin_amdgcn_sched_barrier(0);
}

// ---------------- Stage 1: outer_forward -> (maxval, argmax) per (f, b) ------
// v4: LDS-FREE register GEMM. Round-3 post-mortem: the LDS round trip itself
// (~156 b128 ops/wave ~ 1.9k cy, x32 wave-lifetimes/CU ~ 25 us) plus two
// draining barriers were the cost. In the 4x4-tiled GEMM each operand row is
// consumed by exactly 8 lanes of ONE wave -> duplicated addresses within a
// single global_load_dwordx4 are coalescer-merged for free. So both operands
// stream global->registers directly; norms accumulate in the K-loop from the
// same registers; no barriers until the 32-entry cross-wave argmax combine.
// All accumulation orders (v2f pairing, q-ascending) identical to r3 ->
// bit-exact. ~135 VGPR, 0 LDS in the hot loop.
__global__ __launch_bounds__(128) void stage1_kernel(
    const float* __restrict__ xs, const float* __restrict__ mm0,
    float* __restrict__ maxv1, int* __restrict__ idx1) {
  const int tid = threadIdx.x;
  const int lane = tid & 63;
  const int wave = tid >> 6;
  const int f = blockIdx.x;
  const int mg = lane >> 3, bg = lane & 7;
  const int mrow0 = wave * 32 + mg;  // this lane's first m row (of 4, stride 8)

  __shared__ float bestS[2][32];
  __shared__ int bidxS[2][32];

  const float* mb = mm0 + (size_t)f * 4096 + (size_t)mrow0 * 64;
  const float* xb = xs + (size_t)f * 64 + (size_t)bg * (4096 * 64);

  v2f acc[4][4][2];
  v2f na[4], nx[4];
#pragma unroll
  for (int i = 0; i < 4; ++i) {
    na[i] = (v2f){0.f, 0.f};
    nx[i] = (v2f){0.f, 0.f};
#pragma unroll
    for (int j = 0; j < 4; ++j) {
      acc[i][j][0] = (v2f){0.f, 0.f};
      acc[i][j][1] = (v2f){0.f, 0.f};
    }
  }

#pragma clang loop unroll_count(2)
  for (int q = 0; q < 16; ++q) {
    float4 a[4], bx[4];
#pragma unroll
    for (int i = 0; i < 4; ++i) {
      // 8 distinct rows/wave (x8 lane-dup, merged in the coalescer)
      float4 v = *reinterpret_cast<const float4*>(mb + i * (8 * 64) + 4 * q);
      a[i] = (float4){v.x - 0.5f, v.y - 0.5f, v.z - 0.5f, v.w - 0.5f};
    }
#pragma unroll
    for (int j = 0; j < 4; ++j) {
      float4 v = *reinterpret_cast<const float4*>(
          xb + (size_t)j * (8 * 4096 * 64) + 4 * q);
      bx[j] = (float4){v.x - 0.5f, v.y - 0.5f, v.z - 0.5f, v.w - 0.5f};
    }
    // norms (same v2f pairing + q-ascending order as r3 -> bit-identical)
#pragma unroll
    for (int i = 0; i < 4; ++i) {
      na[i] = (v2f){a[i].x, a[i].y} * (v2f){a[i].x, a[i].y} + na[i];
      na[i] = (v2f){a[i].z, a[i].w} * (v2f){a[i].z, a[i].w} + na[i];
    }
#pragma unroll
    for (int j = 0; j < 4; ++j) {
      nx[j] = (v2f){bx[j].x, bx[j].y} * (v2f){bx[j].x, bx[j].y} + nx[j];
      nx[j] = (v2f){bx[j].z, bx[j].w} * (v2f){bx[j].z, bx[j].w} + nx[j];
    }
    // dots
#pragma unroll
    for (int i = 0; i < 4; ++i)
#pragma unroll
      for (int j = 0; j < 4; ++j) {
        acc[i][j][0] = (v2f){a[i].x, a[i].y} * (v2f){bx[j].x, bx[j].y} + acc[i][j][0];
        acc[i][j][1] = (v2f){a[i].z, a[i].w} * (v2f){bx[j].z, bx[j].w} + acc[i][j][1];
      }
  }

  float mn_i[4], xn_j[4];
#pragma unroll
  for (int i = 0; i < 4; ++i) mn_i[i] = sqrtf(na[i].x + na[i].y);
#pragma unroll
  for (int j = 0; j < 4; ++j) xn_j[j] = sqrtf(nx[j].x + nx[j].y);

  // ---- vals + in-lane argmax over i (rows ascending -> first-max) ----
  float best[4];
  int bidx[4];
#pragma unroll
  for (int j = 0; j < 4; ++j) { best[j] = -__builtin_inff(); bidx[j] = 0; }
#pragma unroll
  for (int i = 0; i < 4; ++i)
#pragma unroll
    for (int j = 0; j < 4; ++j) {
      const float dot =
          acc[i][j][0].x + acc[i][j][0].y + acc[i][j][1].x + acc[i][j][1].y;
      const float val = (dot * 0.5f) / (mn_i[i] * xn_j[j] + RHO) + 0.5f;
      if (val > best[j]) { best[j] = val; bidx[j] = mrow0 + 8 * i; }
    }
  // ---- cross-lane argmax over mg (xor 8/16/32); ties -> lower m ----
#pragma unroll
  for (int off = 8; off < 64; off <<= 1) {
#pragma unroll
    for (int j = 0; j < 4; ++j) {
      const float pv = __shfl_xor(best[j], off, 64);
      const int pm = __shfl_xor(bidx[j], off, 64);
      if (pv > best[j] || (pv == best[j] && pm < bidx[j])) {
        best[j] = pv; bidx[j] = pm;
      }
    }
  }
  if (mg == 0) {  // lanes 0..7 hold b = bg+8j
#pragma unroll
    for (int j = 0; j < 4; ++j) {
      bestS[wave][bg + 8 * j] = best[j];
      bidxS[wave][bg + 8 * j] = bidx[j];
    }
  }
  __syncthreads();
  if (tid < 32) {  // combine halves; ties -> low half (lower m indices)
    const float v0 = bestS[0][tid], v1 = bestS[1][tid];
    const int i0 = bidxS[0][tid], i1 = bidxS[1][tid];
    const bool take1 = (v1 > v0);
    maxv1[f * 32 + tid] = take1 ? v1 : v0;
    idx1[f * 32 + tid] = take1 ? i1 : i0;
  }
}

// -------- shared pipeline macros for stage2/grow (1 child = 16 KB tile) -----
// Swizzled layout per child: element (h,k) at [k*64 + (h^k)] -> staging
// writes and per-(b) column reads are conflict-free.
#define STAGE_WRITE(T, R)                                    \
  do {                                                       \
    _Pragma("unroll") for (int i_ = 0; i_ < 4; ++i_) {       \
      const int g_ = tid + 256 * i_;                         \
      const int h_ = g_ >> 4, k0_ = (g_ & 15) * 4;           \
      (T)[(k0_ + 0) * 64 + (h_ ^ (k0_ + 0))] = (R)[i_].x;    \
      (T)[(k0_ + 1) * 64 + (h_ ^ (k0_ + 1))] = (R)[i_].y;    \
      (T)[(k0_ + 2) * 64 + (h_ ^ (k0_ + 2))] = (R)[i_].z;    \
      (T)[(k0_ + 3) * 64 + (h_ ^ (k0_ + 3))] = (R)[i_].w;    \
    }                                                        \
  } while (0)

#define LOAD_CHILD(R, C)                                     \
  do {                                                       \
    _Pragma("unroll") for (int i_ = 0; i_ < 4; ++i_)         \
        (R)[i_] = src[(C) * 1024 + tid + 256 * i_];          \
  } while (0)

#define COMPUTE_CHILD(C, T)                                              \
  do {                                                                   \
    _Pragma("unroll") for (int i_ = 0; i_ < 8; ++i_) {                   \
      const int b_ = wave * 8 + i_;                                      \
      const int k_ = ixL[(C) * 32 + b_];                                 \
      const float v_ = mvL[(C) * 32 + b_];                               \
      const float w_ = (T)[k_ * 64 + (lane ^ k_)];                       \
      acc[i_] = fmaf(w_, v_, acc[i_]);                                   \
      s2[i_] = fmaf(v_, v_, s2[i_]);                                     \
    }                                                                    \
  } while (0)

// 8-phase register-staged 2-deep pipeline with NON-DRAINING barriers.
// v4: __syncthreads() forced s_waitcnt vmcnt(0) before every s_barrier,
// draining the c+2 prefetch each phase (8 serialized HBM round trips).
// lds_barrier() keeps prefetches in flight; the compiler's automatic
// per-register vmcnt waits before STAGE_WRITE are already counted.
// Summation order over c unchanged -> bit-identical accumulate.
#define PIPELINE_MATMUL()                        \
  do {                                           \
    float4 rE[4], rO[4];                         \
    LOAD_CHILD(rE, 0);                           \
    LOAD_CHILD(rO, 1);                           \
    STAGE_WRITE(tA, rE);                         \
    lds_barrier();                               \
    _Pragma("unroll") for (int cc = 0; cc < 8; cc += 2) { \
      if (cc + 2 < 8) LOAD_CHILD(rE, cc + 2);    \
      COMPUTE_CHILD(cc, tA);                     \
      STAGE_WRITE(tB, rO);                       \
      lds_barrier();                             \
      if (cc + 3 < 8) LOAD_CHILD(rO, cc + 3);    \
      COMPUTE_CHILD(cc + 1, tB);                 \
      if (cc + 2 < 8) { STAGE_WRITE(tA, rE); }   \
      lds_barrier();                             \
    }                                            \
  } while (0)

// ---------------- Stage 2: hidden_forward (512 nodes) -------------------------
__global__ __launch_bounds__(256) void stage2_kernel(
    const float* __restrict__ maxv_in, const int* __restrict__ idx_in,
    const float* __restrict__ mm,
    float* __restrict__ maxv_out, int* __restrict__ idx_out) {
  const int node = blockIdx.x;
  const int lane = threadIdx.x & 63;
  const int wave = threadIdx.x >> 6;
  const int tid = threadIdx.x;

  __shared__ float tA[4096], tB[4096];  // 32 KB double buffer
  __shared__ float mvL[256];
  __shared__ int ixL[256];

  const float4* src = reinterpret_cast<const float4*>(mm + (size_t)node * (8 * 4096));

  // preload the full (c,b) index/value table for this node (coalesced);
  // made visible by the first lds_barrier's lgkmcnt(0).
  mvL[tid] = maxv_in[node * 256 + tid];
  ixL[tid] = idx_in[node * 256 + tid];

  float acc[8], s2[8];
#pragma unroll
  for (int i = 0; i < 8; ++i) { acc[i] = 0.f; s2[i] = 0.f; }

  PIPELINE_MATMUL();

#pragma unroll
  for (int i = 0; i < 8; ++i) {
    const int b = wave * 8 + i;
    const float val = acc[i] / (8.f * sqrtf(s2[i]) + RHO);
    const float mx = wave_max(val);
    unsigned long long t = __ballot(val == mx);
    int j0 = __ffsll((long long)t) - 1;
    if (lane == 0) {
      maxv_out[node * 32 + b] = mx;  // [node][b]
      idx_out[node * 32 + b] = j0;
    }
  }
}

// ---------------- Stage 3 + growth_argmaxi (fused; exact since round 1) -------
__global__ __launch_bounds__(256) void grow_kernel(
    const float* __restrict__ maxv_in, const int* __restrict__ idx_in,
    const float* __restrict__ mm,
    const float* __restrict__ counts, float* __restrict__ out) {
  const int node = blockIdx.x;  // 64 nodes
  const int lane = threadIdx.x & 63;
  const int wave = threadIdx.x >> 6;
  const int tid = threadIdx.x;

  __shared__ float tA[4096], tB[4096];  // 32 KB double buffer
  __shared__ float mvL[256];
  __shared__ int ixL[256];
  __shared__ float hbuf[32 * 64];
  __shared__ float mxvS[32];
  __shared__ int idxS[32];
  __shared__ int trgS[32];
  __shared__ float cntS[64];
  __shared__ int sidxS[64];
  __shared__ int flagS[64];
  __shared__ int compS[64];
  __shared__ int selS[32];
  __shared__ float valS[32];
  __shared__ int keptS[1];

  const float4* src = reinterpret_cast<const float4*>(mm + (size_t)node * (8 * 4096));

  mvL[tid] = maxv_in[node * 256 + tid];
  ixL[tid] = idx_in[node * 256 + tid];

  float acc[8], s2[8];
#pragma unroll
  for (int i = 0; i < 8; ++i) { acc[i] = 0.f; s2[i] = 0.f; }

  PIPELINE_MATMUL();

#pragma unroll
  for (int i = 0; i < 8; ++i) {
    const int b = wave * 8 + i;
    const float val = acc[i] / (8.f * sqrtf(s2[i]) + RHO);
    const float mx = wave_max(val);
    unsigned long long t = __ballot(val == mx);
    int j0 = __ffsll((long long)t) - 1;
    hbuf[b * 64 + lane] = val;
    unsigned long long big = __ballot(val > THRESH);
    if (lane == 0) {
      mxvS[b] = mx; idxS[b] = j0; trgS[b] = (big == 0ULL) ? 1 : 0;
    }
  }

  if (tid < 64) { cntS[tid] = counts[node * 64 + tid]; flagS[tid] = 0; }
  __syncthreads();
  if (tid < 64) {  // stable ascending argsort of counts row
    float cl = cntS[tid];
    int rank = 0;
    for (int j = 0; j < 64; ++j) {
      float cj = cntS[j];
      rank += (cj < cl || (cj == cl && j < tid)) ? 1 : 0;
    }
    sidxS[rank] = tid;
  }
  __syncthreads();
  if (tid < 32) {  // reserved marks from non-triggered batches
    const int b = tid;
    if (!trgS[b]) {
      int j = idxS[b];
      float a = fabsf(mxvS[b]);
      int res;
      if (a > EPSV) res = j;             // unique positive max -> argsort[-1]=j
      else if (a == 0.f) res = 63;       // all-zero row: stable last = 63
      else if (a == EPSV) res = j;       // +inf at j
      else res = (j == 63) ? 62 : 63;    // negative entry: last zero wins
      flagS[res] = 1;
    }
  }
  __syncthreads();
  if (wave == 0) {  // stable compaction (move MARK to back)
    int s = sidxS[lane];
    int keep = flagS[s] ? 0 : 1;
    unsigned long long kb = __ballot(keep);
    int pos = __popcll(kb & ((1ULL << lane) - 1ULL));
    if (keep) compS[pos] = s;
    if (lane == 0) keptS[0] = __popcll(kb);
  }
  __syncthreads();
  if (tid < 32) {  // final index + value per batch
    const int b = tid;
    int fin = (b < keptS[0]) ? compS[b] : sidxS[b];
    int idxb; float a;
    if (trgS[b]) {
      idxb = fin;
      float v = hbuf[b * 64 + idxb];
      if (v == 0.f) v = 1.f;
      a = fabsf(v);
    } else {
      idxb = idxS[b];
      a = fabsf(mxvS[b]);
    }
    selS[b] = idxb;
    valS[b] = a / (a - EPSV);
  }
  __syncthreads();
#pragma unroll
  for (int r = 0; r < 8; ++r) {  // write (32,64) one-hot rows for this node
    int i = tid + 256 * r;
    int b = i >> 6, h = i & 63;
    out[((size_t)b * 64 + node) * 64 + h] = (h == selS[b]) ? valS[b] : 0.f;
  }
}

extern "C" void kernel_launch(void* const* d_in, const int* in_sizes, int n_in,
                              void* d_out, int out_size, void* d_ws, size_t ws_size,
                              hipStream_t stream) {
  const float* xs = (const float*)d_in[0];      // (32, 4096, 64)
  const float* mm0 = (const float*)d_in[1];     // (4096, 64, 64)
  const float* mm1 = (const float*)d_in[2];     // (512, 8, 64, 64)
  const float* mm2 = (const float*)d_in[3];     // (64, 8, 64, 64)
  const float* counts = (const float*)d_in[4];  // (64, 64)
  float* out = (float*)d_out;                   // (32, 64, 64)
  char* ws = (char*)d_ws;

  float* maxv1 = (float*)(ws + 0);        // [4096][32] f32
  int* idx1 = (int*)(ws + 524288);        // [4096][32] i32
  float* maxv2 = (float*)(ws + 1048576);  // [512][32] f32
  int* idx2 = (int*)(ws + 1114112);       // [512][32] i32

  stage1_kernel<<<dim3(4096), dim3(128), 0, stream>>>(xs, mm0, maxv1, idx1);
  stage2_kernel<<<dim3(512), dim3(256), 0, stream>>>(maxv1, idx1, mm1, maxv2, idx2);
  grow_kernel<<<dim3(64), dim3(256), 0, stream>>>(maxv2, idx2, mm2, counts, out);
}

// Round 5
// 231.300 us; speedup vs baseline: 1.0694x; 1.0694x over previous
//
#include <hip/hip_runtime.h>
#include <cstdint>
#include <cstddef>

#define RHO 1e-8f
#define EPSV 1e-8f
#define THRESH 0.9f

typedef float v2f __attribute__((ext_vector_type(2)));

__device__ __forceinline__ float wave_max(float v) {
#pragma unroll
  for (int off = 1; off < 64; off <<= 1) v = fmaxf(v, __shfl_xor(v, off, 64));
  return v;
}

// Raw workgroup barrier WITHOUT the compiler's vmcnt(0) drain: only LDS ops
// must be visible across it (lgkmcnt(0)); outstanding global prefetches stay
// in flight (T3/T4 counted-wait pattern). sched_barrier(0) fences the machine
// scheduler (rule #18); the "memory" clobber fences IR-level motion.
__device__ __forceinline__ void lds_barrier() {
  asm volatile("s_waitcnt lgkmcnt(0)" ::: "memory");
  __builtin_amdgcn_sched_barrier(0);
  __builtin_amdgcn_s_barrier();
  __builtin_amdgcn_sched_barrier(0);
}

// ---------------- Stage 1: outer_forward -> (maxval, argmax) per (f, b) ------
// v5: r3's LDS-staged register GEMM (51 us, best) + T14 4-field-per-block
// software pipeline. Round-4 post-mortem: per-lane scattered global loads
// fragment into 8 transactions/instr -> revert to coalesced staging.
// Remaining r3 gap vs its ~22 us LDS-pipe floor was exposed staging latency
// (serial stage->barrier->compute per block). Now each block processes 4
// fields: while field k's K-loop runs, field k+1's m/x sit in prefetch
// registers (loaded coalesced a full field earlier, ~1.3 us of slack) and are
// ds_written into a double-buffered m-tile; x is single-buffered and written
// after the post-compute barrier (WAR-safe). All barriers are lgkmcnt-only,
// so prefetch loads are never drained. LDS = 2x16KB (m) + 8KB (x) = 40 KB
// -> 4 blocks/CU. Lane grid 16mg x 4bg, wave = 16 batches x all 64 m-rows:
// argmax is wave-local (no cross-wave combine / bestS). All accumulation
// orders (v2f pairing, q-ascending) and tie-breaks (strict >, min index)
// identical to the passing r3/r4 kernels -> bit-exact.
__global__ __launch_bounds__(128) void stage1_kernel(
    const float* __restrict__ xs, const float* __restrict__ mm0,
    float* __restrict__ maxv1, int* __restrict__ idx1) {
  const int tid = threadIdx.x;
  const int lane = tid & 63;
  const int wave = tid >> 6;
  const int mg = lane & 15, bg = lane >> 4;  // 16m x 4b lane grid

  __shared__ float mS[2][4096];  // 32 KB, double-buffered, swizzled
  __shared__ float xS[2048];     // 8 KB, single-buffered, swizzled

  const int f0 = blockIdx.x * 4;

  float4 Rm[8], Rx[4];

  // coalesced prefetch: 16-lane groups read contiguous 256B rows
#define S1_LOADM(F)                                                      \
  do {                                                                   \
    const float* mf_ = mm0 + (size_t)(F)*4096;                           \
    _Pragma("unroll") for (int i_ = 0; i_ < 8; ++i_) {                   \
      const int g_ = tid + 128 * i_;                                     \
      Rm[i_] = *reinterpret_cast<const float4*>(mf_ + g_ * 4);           \
    }                                                                    \
  } while (0)

#define S1_LOADX(F)                                                      \
  do {                                                                   \
    _Pragma("unroll") for (int i_ = 0; i_ < 4; ++i_) {                   \
      const int g_ = tid + 128 * i_;                                     \
      const int b_ = g_ >> 4, q_ = g_ & 15;                              \
      Rx[i_] = *reinterpret_cast<const float4*>(                         \
          xs + ((size_t)b_ * 4096 + (F)) * 64 + q_ * 4);                 \
    }                                                                    \
  } while (0)

  // swizzled float4 slot(r,q) = r*16 + (q ^ (r&15)): writes and reads hit
  // the minimal number of bank rounds (same map as r3). -0.5 applied here.
#define S1_WRITEM(P)                                                     \
  do {                                                                   \
    _Pragma("unroll") for (int i_ = 0; i_ < 8; ++i_) {                   \
      const int g_ = tid + 128 * i_;                                     \
      const int r_ = g_ >> 4, q_ = g_ & 15;                              \
      float4 w_ = {Rm[i_].x - 0.5f, Rm[i_].y - 0.5f, Rm[i_].z - 0.5f,    \
                   Rm[i_].w - 0.5f};                                     \
      *reinterpret_cast<float4*>(                                        \
          &mS[P][(r_ * 16 + (q_ ^ (r_ & 15))) * 4]) = w_;                \
    }                                                                    \
  } while (0)

#define S1_WRITEX()                                                      \
  do {                                                                   \
    _Pragma("unroll") for (int i_ = 0; i_ < 4; ++i_) {                   \
      const int g_ = tid + 128 * i_;                                     \
      const int b_ = g_ >> 4, q_ = g_ & 15;                              \
      float4 w_ = {Rx[i_].x - 0.5f, Rx[i_].y - 0.5f, Rx[i_].z - 0.5f,    \
                   Rx[i_].w - 0.5f};                                     \
      *reinterpret_cast<float4*>(                                        \
          &xS[(b_ * 16 + (q_ ^ (b_ & 15))) * 4]) = w_;                   \
    }                                                                    \
  } while (0)

  // prologue: stage field 0, prefetch field 1
  S1_LOADM(f0);
  S1_LOADX(f0);
  S1_WRITEM(0);
  S1_WRITEX();
  S1_LOADM(f0 + 1);
  S1_LOADX(f0 + 1);
  lds_barrier();

#pragma unroll
  for (int k = 0; k < 4; ++k) {
    const int f = f0 + k;
    const float* mT = mS[k & 1];

    v2f acc[4][4][2];
    v2f na[4], nx[4];
#pragma unroll
    for (int i = 0; i < 4; ++i) {
      na[i] = (v2f){0.f, 0.f};
      nx[i] = (v2f){0.f, 0.f};
#pragma unroll
      for (int j = 0; j < 4; ++j) {
        acc[i][j][0] = (v2f){0.f, 0.f};
        acc[i][j][1] = (v2f){0.f, 0.f};
      }
    }

    // ---- K-loop: rows mg+16i, batches wave*16 + bg+4j ----
#pragma unroll
    for (int q = 0; q < 16; ++q) {
      float4 a[4], bx[4];
#pragma unroll
      for (int i = 0; i < 4; ++i) {
        const int r = mg + 16 * i;
        a[i] = *reinterpret_cast<const float4*>(
            &mT[(r * 16 + (q ^ (r & 15))) * 4]);
      }
#pragma unroll
      for (int j = 0; j < 4; ++j) {
        const int b = wave * 16 + bg + 4 * j;
        bx[j] = *reinterpret_cast<const float4*>(
            &xS[(b * 16 + (q ^ (b & 15))) * 4]);
      }
      // norms (q-ascending, same v2f pairing as r3/r4 -> bit-identical)
#pragma unroll
      for (int i = 0; i < 4; ++i) {
        na[i] = (v2f){a[i].x, a[i].y} * (v2f){a[i].x, a[i].y} + na[i];
        na[i] = (v2f){a[i].z, a[i].w} * (v2f){a[i].z, a[i].w} + na[i];
      }
#pragma unroll
      for (int j = 0; j < 4; ++j) {
        nx[j] = (v2f){bx[j].x, bx[j].y} * (v2f){bx[j].x, bx[j].y} + nx[j];
        nx[j] = (v2f){bx[j].z, bx[j].w} * (v2f){bx[j].z, bx[j].w} + nx[j];
      }
      // dots
#pragma unroll
      for (int i = 0; i < 4; ++i)
#pragma unroll
        for (int j = 0; j < 4; ++j) {
          acc[i][j][0] =
              (v2f){a[i].x, a[i].y} * (v2f){bx[j].x, bx[j].y} + acc[i][j][0];
          acc[i][j][1] =
              (v2f){a[i].z, a[i].w} * (v2f){bx[j].z, bx[j].w} + acc[i][j][1];
        }
    }

    // stage next field's m tile into the other buffer (overlaps epilogue)
    if (k < 3) S1_WRITEM((k + 1) & 1);

    float mn_i[4], xn_j[4];
#pragma unroll
    for (int i = 0; i < 4; ++i) mn_i[i] = sqrtf(na[i].x + na[i].y);
#pragma unroll
    for (int j = 0; j < 4; ++j) xn_j[j] = sqrtf(nx[j].x + nx[j].y);

    // vals + in-lane argmax over i (rows ascending -> first-max)
    float best[4];
    int bidx[4];
#pragma unroll
    for (int j = 0; j < 4; ++j) {
      best[j] = -__builtin_inff();
      bidx[j] = 0;
    }
#pragma unroll
    for (int i = 0; i < 4; ++i)
#pragma unroll
      for (int j = 0; j < 4; ++j) {
        const float dot =
            acc[i][j][0].x + acc[i][j][0].y + acc[i][j][1].x + acc[i][j][1].y;
        const float val = (dot * 0.5f) / (mn_i[i] * xn_j[j] + RHO) + 0.5f;
        if (val > best[j]) {
          best[j] = val;
          bidx[j] = mg + 16 * i;
        }
      }
    // cross-lane argmax over mg (xor 1/2/4/8, same bg); ties -> lower m
#pragma unroll
    for (int off = 1; off < 16; off <<= 1) {
#pragma unroll
      for (int j = 0; j < 4; ++j) {
        const float pv = __shfl_xor(best[j], off, 64);
        const int pm = __shfl_xor(bidx[j], off, 64);
        if (pv > best[j] || (pv == best[j] && pm < bidx[j])) {
          best[j] = pv;
          bidx[j] = pm;
        }
      }
    }

    if (k < 3) lds_barrier();  // b_k: all xS/mS[k&1] reads done
    if (k < 3) S1_WRITEX();    // stage next field's x (single buffer)
    if (k < 2) {               // prefetch field k+2
      S1_LOADM(f0 + k + 2);
      S1_LOADX(f0 + k + 2);
    }
    if (mg == 0) {  // lanes 0/16/32/48: bg = lane>>4
#pragma unroll
      for (int j = 0; j < 4; ++j) {
        const int b = wave * 16 + bg + 4 * j;
        maxv1[f * 32 + b] = best[j];
        idx1[f * 32 + b] = bidx[j];
      }
    }
    if (k < 3) lds_barrier();  // a_{k+1}: next tiles visible
  }

#undef S1_LOADM
#undef S1_LOADX
#undef S1_WRITEM
#undef S1_WRITEX
}

// -------- shared pipeline macros for stage2/grow (1 child = 16 KB tile) -----
// Swizzled layout per child: element (h,k) at [k*64 + (h^k)] -> staging
// writes and per-(b) column reads are conflict-free.
#define STAGE_WRITE(T, R)                                    \
  do {                                                       \
    _Pragma("unroll") for (int i_ = 0; i_ < 4; ++i_) {       \
      const int g_ = tid + 256 * i_;                         \
      const int h_ = g_ >> 4, k0_ = (g_ & 15) * 4;           \
      (T)[(k0_ + 0) * 64 + (h_ ^ (k0_ + 0))] = (R)[i_].x;    \
      (T)[(k0_ + 1) * 64 + (h_ ^ (k0_ + 1))] = (R)[i_].y;    \
      (T)[(k0_ + 2) * 64 + (h_ ^ (k0_ + 2))] = (R)[i_].z;    \
      (T)[(k0_ + 3) * 64 + (h_ ^ (k0_ + 3))] = (R)[i_].w;    \
    }                                                        \
  } while (0)

#define LOAD_CHILD(R, C)                                     \
  do {                                                       \
    _Pragma("unroll") for (int i_ = 0; i_ < 4; ++i_)         \
        (R)[i_] = src[(C) * 1024 + tid + 256 * i_];          \
  } while (0)

#define COMPUTE_CHILD(C, T)                                              \
  do {                                                                   \
    _Pragma("unroll") for (int i_ = 0; i_ < 8; ++i_) {                   \
      const int b_ = wave * 8 + i_;                                      \
      const int k_ = ixL[(C) * 32 + b_];                                 \
      const float v_ = mvL[(C) * 32 + b_];                               \
      const float w_ = (T)[k_ * 64 + (lane ^ k_)];                       \
      acc[i_] = fmaf(w_, v_, acc[i_]);                                   \
      s2[i_] = fmaf(v_, v_, s2[i_]);                                     \
    }                                                                    \
  } while (0)

// 8-phase register-staged 2-deep pipeline with NON-DRAINING barriers.
// Summation order over c unchanged -> bit-identical accumulate.
#define PIPELINE_MATMUL()                        \
  do {                                           \
    float4 rE[4], rO[4];                         \
    LOAD_CHILD(rE, 0);                           \
    LOAD_CHILD(rO, 1);                           \
    STAGE_WRITE(tA, rE);                         \
    lds_barrier();                               \
    _Pragma("unroll") for (int cc = 0; cc < 8; cc += 2) { \
      if (cc + 2 < 8) LOAD_CHILD(rE, cc + 2);    \
      COMPUTE_CHILD(cc, tA);                     \
      STAGE_WRITE(tB, rO);                       \
      lds_barrier();                             \
      if (cc + 3 < 8) LOAD_CHILD(rO, cc + 3);    \
      COMPUTE_CHILD(cc + 1, tB);                 \
      if (cc + 2 < 8) { STAGE_WRITE(tA, rE); }   \
      lds_barrier();                             \
    }                                            \
  } while (0)

// ---------------- Stage 2: hidden_forward (512 nodes) -------------------------
__global__ __launch_bounds__(256) void stage2_kernel(
    const float* __restrict__ maxv_in, const int* __restrict__ idx_in,
    const float* __restrict__ mm,
    float* __restrict__ maxv_out, int* __restrict__ idx_out) {
  const int node = blockIdx.x;
  const int lane = threadIdx.x & 63;
  const int wave = threadIdx.x >> 6;
  const int tid = threadIdx.x;

  __shared__ float tA[4096], tB[4096];  // 32 KB double buffer
  __shared__ float mvL[256];
  __shared__ int ixL[256];

  const float4* src = reinterpret_cast<const float4*>(mm + (size_t)node * (8 * 4096));

  // preload the full (c,b) index/value table for this node (coalesced);
  // made visible by the first lds_barrier's lgkmcnt(0).
  mvL[tid] = maxv_in[node * 256 + tid];
  ixL[tid] = idx_in[node * 256 + tid];

  float acc[8], s2[8];
#pragma unroll
  for (int i = 0; i < 8; ++i) { acc[i] = 0.f; s2[i] = 0.f; }

  PIPELINE_MATMUL();

#pragma unroll
  for (int i = 0; i < 8; ++i) {
    const int b = wave * 8 + i;
    const float val = acc[i] / (8.f * sqrtf(s2[i]) + RHO);
    const float mx = wave_max(val);
    unsigned long long t = __ballot(val == mx);
    int j0 = __ffsll((long long)t) - 1;
    if (lane == 0) {
      maxv_out[node * 32 + b] = mx;  // [node][b]
      idx_out[node * 32 + b] = j0;
    }
  }
}

// ---------------- Stage 3 + growth_argmaxi (fused; exact since round 1) -------
__global__ __launch_bounds__(256) void grow_kernel(
    const float* __restrict__ maxv_in, const int* __restrict__ idx_in,
    const float* __restrict__ mm,
    const float* __restrict__ counts, float* __restrict__ out) {
  const int node = blockIdx.x;  // 64 nodes
  const int lane = threadIdx.x & 63;
  const int wave = threadIdx.x >> 6;
  const int tid = threadIdx.x;

  __shared__ float tA[4096], tB[4096];  // 32 KB double buffer
  __shared__ float mvL[256];
  __shared__ int ixL[256];
  __shared__ float hbuf[32 * 64];
  __shared__ float mxvS[32];
  __shared__ int idxS[32];
  __shared__ int trgS[32];
  __shared__ float cntS[64];
  __shared__ int sidxS[64];
  __shared__ int flagS[64];
  __shared__ int compS[64];
  __shared__ int selS[32];
  __shared__ float valS[32];
  __shared__ int keptS[1];

  const float4* src = reinterpret_cast<const float4*>(mm + (size_t)node * (8 * 4096));

  mvL[tid] = maxv_in[node * 256 + tid];
  ixL[tid] = idx_in[node * 256 + tid];

  float acc[8], s2[8];
#pragma unroll
  for (int i = 0; i < 8; ++i) { acc[i] = 0.f; s2[i] = 0.f; }

  PIPELINE_MATMUL();

#pragma unroll
  for (int i = 0; i < 8; ++i) {
    const int b = wave * 8 + i;
    const float val = acc[i] / (8.f * sqrtf(s2[i]) + RHO);
    const float mx = wave_max(val);
    unsigned long long t = __ballot(val == mx);
    int j0 = __ffsll((long long)t) - 1;
    hbuf[b * 64 + lane] = val;
    unsigned long long big = __ballot(val > THRESH);
    if (lane == 0) {
      mxvS[b] = mx; idxS[b] = j0; trgS[b] = (big == 0ULL) ? 1 : 0;
    }
  }

  if (tid < 64) { cntS[tid] = counts[node * 64 + tid]; flagS[tid] = 0; }
  __syncthreads();
  if (tid < 64) {  // stable ascending argsort of counts row
    float cl = cntS[tid];
    int rank = 0;
    for (int j = 0; j < 64; ++j) {
      float cj = cntS[j];
      rank += (cj < cl || (cj == cl && j < tid)) ? 1 : 0;
    }
    sidxS[rank] = tid;
  }
  __syncthreads();
  if (tid < 32) {  // reserved marks from non-triggered batches
    const int b = tid;
    if (!trgS[b]) {
      int j = idxS[b];
      float a = fabsf(mxvS[b]);
      int res;
      if (a > EPSV) res = j;             // unique positive max -> argsort[-1]=j
      else if (a == 0.f) res = 63;       // all-zero row: stable last = 63
      else if (a == EPSV) res = j;       // +inf at j
      else res = (j == 63) ? 62 : 63;    // negative entry: last zero wins
      flagS[res] = 1;
    }
  }
  __syncthreads();
  if (wave == 0) {  // stable compaction (move MARK to back)
    int s = sidxS[lane];
    int keep = flagS[s] ? 0 : 1;
    unsigned long long kb = __ballot(keep);
    int pos = __popcll(kb & ((1ULL << lane) - 1ULL));
    if (keep) compS[pos] = s;
    if (lane == 0) keptS[0] = __popcll(kb);
  }
  __syncthreads();
  if (tid < 32) {  // final index + value per batch
    const int b = tid;
    int fin = (b < keptS[0]) ? compS[b] : sidxS[b];
    int idxb; float a;
    if (trgS[b]) {
      idxb = fin;
      float v = hbuf[b * 64 + idxb];
      if (v == 0.f) v = 1.f;
      a = fabsf(v);
    } else {
      idxb = idxS[b];
      a = fabsf(mxvS[b]);
    }
    selS[b] = idxb;
    valS[b] = a / (a - EPSV);
  }
  __syncthreads();
#pragma unroll
  for (int r = 0; r < 8; ++r) {  // write (32,64) one-hot rows for this node
    int i = tid + 256 * r;
    int b = i >> 6, h = i & 63;
    out[((size_t)b * 64 + node) * 64 + h] = (h == selS[b]) ? valS[b] : 0.f;
  }
}

extern "C" void kernel_launch(void* const* d_in, const int* in_sizes, int n_in,
                              void* d_out, int out_size, void* d_ws, size_t ws_size,
                              hipStream_t stream) {
  const float* xs = (const float*)d_in[0];      // (32, 4096, 64)
  const float* mm0 = (const float*)d_in[1];     // (4096, 64, 64)
  const float* mm1 = (const float*)d_in[2];     // (512, 8, 64, 64)
  const float* mm2 = (const float*)d_in[3];     // (64, 8, 64, 64)
  const float* counts = (const float*)d_in[4];  // (64, 64)
  float* out = (float*)d_out;                   // (32, 64, 64)
  char* ws = (char*)d_ws;

  float* maxv1 = (float*)(ws + 0);        // [4096][32] f32
  int* idx1 = (int*)(ws + 524288);        // [4096][32] i32
  float* maxv2 = (float*)(ws + 1048576);  // [512][32] f32
  int* idx2 = (int*)(ws + 1114112);       // [512][32] i32

  stage1_kernel<<<dim3(1024), dim3(128), 0, stream>>>(xs, mm0, maxv1, idx1);
  stage2_kernel<<<dim3(512), dim3(256), 0, stream>>>(maxv1, idx1, mm1, maxv2, idx2);
  grow_kernel<<<dim3(64), dim3(256), 0, stream>>>(maxv2, idx2, mm2, counts, out);
}